// Round 8
// baseline (371.284 us; speedup 1.0000x reference)
//
#include <hip/hip_runtime.h>
#include <hip/hip_bf16.h>
#include <stdint.h>

#define ENC_DIM 2048
#define DEC_DIM 512
#define ATT_DIM 512
#define BATCH   256
#define PIX     196
#define M_TOTAL (BATCH*PIX)   // 50176
#define NT      (ENC_DIM/64)  // 32 K-tiles

typedef unsigned short u16;
typedef __attribute__((ext_vector_type(8))) short  bf16x8;
typedef __attribute__((ext_vector_type(4))) float  f32x4;

// ---------- helpers ----------
__device__ __forceinline__ void gll16(const void* g, void* l) {
    __builtin_amdgcn_global_load_lds(
        (const __attribute__((address_space(1))) unsigned int*)g,
        (__attribute__((address_space(3))) unsigned int*)l,
        16, 0, 0);
}

union Pack8 {
    uint4 u;
    __hip_bfloat16 h[8];
};

__device__ __forceinline__ uint4 cvt8(float4 a, float4 b) {
    Pack8 p;
    p.h[0] = __float2bfloat16(a.x); p.h[1] = __float2bfloat16(a.y);
    p.h[2] = __float2bfloat16(a.z); p.h[3] = __float2bfloat16(a.w);
    p.h[4] = __float2bfloat16(b.x); p.h[5] = __float2bfloat16(b.y);
    p.h[6] = __float2bfloat16(b.z); p.h[7] = __float2bfloat16(b.w);
    return p.u;
}

// ---------- kernel 1: W_enc fp32 -> bf16 ----------
__global__ void k_convert(const float* __restrict__ W, u16* __restrict__ Wb) {
    int idx = blockIdx.x * 256 + threadIdx.x;
    const float4* s = (const float4*)W + (size_t)idx * 2;
    ((uint4*)Wb)[idx] = cvt8(s[0], s[1]);
}

// ---------- kernel 2: att2[b,a] = dec[b,:].W_dec[a,:] + b_enc[a] + b_dec[a] ----------
__global__ void k_att2(const float* __restrict__ dec, const float* __restrict__ Wd,
                       const float* __restrict__ b_enc, const float* __restrict__ b_dec,
                       float* __restrict__ att2f) {
    int b = blockIdx.x;
    int t = threadIdx.x;
    __shared__ float dec_s[DEC_DIM];
    ((float2*)dec_s)[t] = ((const float2*)(dec + (size_t)b * DEC_DIM))[t];
    __syncthreads();
    #pragma unroll
    for (int rep = 0; rep < 2; ++rep) {
        int a = t + rep * 256;
        const float4* w = (const float4*)(Wd + (size_t)a * DEC_DIM);
        float acc = 0.f;
        #pragma unroll 4
        for (int e = 0; e < DEC_DIM / 4; ++e) {
            float4 wv = w[e];
            float4 dv = ((const float4*)dec_s)[e];
            acc += wv.x * dv.x + wv.y * dv.y + wv.z * dv.z + wv.w * dv.w;
        }
        att2f[(size_t)b * ATT_DIM + a] = acc + b_enc[a] + b_dec[a];
    }
}

// ---------- kernel 3: fused GEMM, BN=512, BM=64 -> 2 blocks/CU (TLP) ----------
// BM=64, BN=512, BK=64. 512 threads = 8 waves (2M x 4N), per-wave 32x128.
// LDS 80KB: A dbuf 2x8KB (reg-staged fp32->bf16, swizzled write),
//           B single 64KB (gll16, pre-swizzled source; Wb is L2-resident).
// 2 blocks/CU: the other block's waves hide VMC/barrier/A-pacing latency.
// vmcnt FIFO discipline (R6 fix): gll16 issued BEFORE A prefetch loads,
// so VMC(2) completes the 8 gll16 (oldest) and keeps 2 A-loads in flight.

#define FENCE  asm volatile("" ::: "memory")
#define LGKM0  asm volatile("s_waitcnt lgkmcnt(0)" ::: "memory")
#define VMC(N) asm volatile("s_waitcnt vmcnt(" #N ")" ::: "memory")
#define SBARF  do { FENCE; __builtin_amdgcn_s_barrier(); FENCE; } while (0)

// 2 fp32x4 loads for A-tile KT: thread t covers row t>>3, k-octet t&7
#define ISSUE_A(KT, F) do { const float* _p = a_src + (size_t)(KT) * 64;               \
    F[0] = *(const float4*)(_p);                                                       \
    F[1] = *(const float4*)(_p + 4); } while (0)

// cvt + 1 swizzled ds_write_b128 into As[Q] (compiler inserts the vmcnt
// wait for F's loads here -> A-pacing point, 1 tile of slack)
#define WRITE_A(Q, F) do {                                                             \
    *(uint4*)(&As[Q][aw_off]) = cvt8(F[0], F[1]); } while (0)

// 8 gll16 staging the 512x64 B-tile KT (pre-swizzled source, linear dest)
#define STAGE_B(KT) do { const u16* _b = b_src + (size_t)(KT) * 64;                    \
    _Pragma("unroll") for (int s = 0; s < 8; ++s)                                      \
        gll16(_b + (size_t)s * 64 * ENC_DIM, &Bs[s * 4096 + b_dst]); } while (0)

#define COMPUTE(P) do {                                                                \
    _Pragma("unroll") for (int ks = 0; ks < 2; ++ks) {                                 \
        const int _axo = ks ? axo1 : axo0;                                             \
        bf16x8 af[2], bf[8];                                                           \
        _Pragma("unroll") for (int m = 0; m < 2; ++m)                                  \
            af[m] = *(const bf16x8*)(&As[P][a_row_off + m * 1024 + _axo]);             \
        _Pragma("unroll") for (int n = 0; n < 8; ++n)                                  \
            bf[n] = *(const bf16x8*)(&Bs[b_row_off + n * 1024 + _axo]);                \
        __builtin_amdgcn_s_setprio(1);                                                 \
        _Pragma("unroll") for (int m = 0; m < 2; ++m)                                  \
            _Pragma("unroll") for (int n = 0; n < 8; ++n)                              \
                acc[m][n] = __builtin_amdgcn_mfma_f32_16x16x32_bf16(af[m], bf[n], acc[m][n], 0, 0, 0); \
        __builtin_amdgcn_s_setprio(0);                                                 \
    } } while (0)

__global__ void __launch_bounds__(512, 2)
k_gemm(const float* __restrict__ enc, const u16* __restrict__ Wb,
       const float* __restrict__ att2f, const float* __restrict__ Wfull,
       float* __restrict__ att_part) {
    const int mb = blockIdx.x;                 // 784 blocks, BN covers all of N
    const int t  = threadIdx.x;
    const int lane = t & 63, wave = t >> 6;
    const int wm = wave >> 2, wn = wave & 3;   // 2M x 4N wave grid
    const int fr = lane & 15, fq = lane >> 4;

    __shared__ u16 As[2][64 * 64];   // 2 x 8 KB
    __shared__ u16 Bs[512 * 64];     // 64 KB (single-buffered)

    f32x4 acc[2][8];
    #pragma unroll
    for (int m = 0; m < 2; ++m)
        #pragma unroll
        for (int n = 0; n < 8; ++n)
            acc[m][n] = (f32x4){0.f, 0.f, 0.f, 0.f};

    // A staging: thread t covers row t>>3 (0..63), k-octet t&7
    const int arow  = t >> 3;
    const int aslot = t & 7;
    const float* a_src = enc + (size_t)(mb * 64 + arow) * ENC_DIM + aslot * 8;
    const int aw_off = arow * 64 + ((aslot ^ (arow & 7))) * 8;

    // B staging via gll16: lane covers row s*64 + wave*8 + (l>>3), slot l&7;
    // source octet pre-swizzled (rule #21), dest linear (HW adds lane*16B)
    const int brl = lane >> 3, bslot = lane & 7;
    const u16* b_src = Wb + (size_t)(wave * 8 + brl) * ENC_DIM + ((bslot ^ brl)) * 8;
    const int b_dst = (wave * 8) * 64;

    // fragment reads: A row = wm*32 + m*16 + fr; B row = wn*128 + n*16 + fr;
    // slot = ((ks<<2)|fq) ^ (fr&7)
    const int r7 = fr & 7;
    const int axo0 = ((fq    ) ^ r7) * 8;
    const int axo1 = ((fq | 4) ^ r7) * 8;
    const int a_row_off = (wm * 32 + fr) * 64;
    const int b_row_off = (wn * 128 + fr) * 64;

    float4 eE[2], eO[2];   // 2-deep A-reg pipeline, parity-named (rule #20)

    // ---- prologue (gll16 before A-issue: FIFO order) ----
    ISSUE_A(0, eE); FENCE;
    STAGE_B(0);
    WRITE_A(0, eE);        // compiler waits A(0) regs (gll16 newer, stay)
    FENCE; ISSUE_A(1, eO);
    VMC(2);                // completes 8 gll16(0); keeps A(1) x2 in flight
    LGKM0;
    SBARF;                 // Bs=B(0), As[0]=A(0) visible

    // ---- main loop: tiles 0..29 ----
    for (int kt = 0; kt < NT - 2; kt += 2) {
        // even tile kt (As[0])
        WRITE_A(1, eO);                // waits A(kt+1) regs -> A-pacing point
        COMPUTE(0);
        SBARF;                         // Bs readers done
        STAGE_B(kt + 1); FENCE;        // gll16 first (oldest in FIFO)
        ISSUE_A(kt + 2, eE);           // A prefetch second (newest)
        VMC(2);                        // completes gll16(kt+1); keeps A(kt+2)
        LGKM0;
        SBARF;                         // staging visible
        // odd tile kt+1 (As[1])
        WRITE_A(0, eE);
        COMPUTE(1);
        SBARF;
        STAGE_B(kt + 2); FENCE;
        ISSUE_A(kt + 3, eO);
        VMC(2);
        LGKM0;
        SBARF;
    }

    // ---- tile 30 (As[0]): write A(31), stage B(31), no more issues ----
    {
        WRITE_A(1, eO);                // waits A(31) regs
        COMPUTE(0);
        SBARF;
        STAGE_B(31);
        VMC(0);                        // full drain
        LGKM0;
        SBARF;
    }
    // ---- tile 31 (As[1]): pure compute ----
    COMPUTE(1);

    // ---- epilogue: +att2, relu, dot W_full, 16-lane reduce ----
    // C/D layout: col = lane&15, row = (lane>>4)*4 + reg  [m89/m91]
    const int row_base = mb * 64 + wm * 32 + fq * 4;
    const int col_base = wn * 128 + fr;
    float wf[8];
    #pragma unroll
    for (int n = 0; n < 8; ++n) wf[n] = Wfull[col_base + n * 16];

    #pragma unroll
    for (int m = 0; m < 2; ++m) {
        #pragma unroll
        for (int r = 0; r < 4; ++r) {
            const int grow = row_base + m * 16 + r;
            const int bidx = grow / PIX;
            const float* a2 = att2f + (size_t)bidx * ATT_DIM;
            float ssum = 0.f;
            #pragma unroll
            for (int n = 0; n < 8; ++n) {
                float v = acc[m][n][r] + a2[col_base + n * 16];
                v = fmaxf(v, 0.f);
                ssum += v * wf[n];
            }
            #pragma unroll
            for (int off = 1; off < 16; off <<= 1)
                ssum += __shfl_xor(ssum, off, 64);
            if (fr == 0)
                att_part[(size_t)wn * M_TOTAL + grow] = ssum;
        }
    }
}

// ---------- kernel 4: per-b softmax over 196 + alpha-weighted enc reduction ----------
__global__ void k_soft(const float* __restrict__ att_part, const float* __restrict__ enc,
                       float* __restrict__ out) {
    const int b  = blockIdx.x >> 1;
    const int ec = blockIdx.x & 1;   // e-chunk of 1024
    const int t  = threadIdx.x;
    __shared__ float red[256];
    __shared__ float alpha_s[PIX];

    float myatt = -1e30f;
    if (t < PIX) {
        float s = 0.f;
        #pragma unroll
        for (int j = 0; j < 4; ++j) s += att_part[(size_t)j * M_TOTAL + b * PIX + t];
        myatt = s;
    }
    red[t] = myatt;
    __syncthreads();
    for (int o = 128; o > 0; o >>= 1) {
        if (t < o) red[t] = fmaxf(red[t], red[t + o]);
        __syncthreads();
    }
    const float mx = red[0];
    __syncthreads();
    float e = 0.f;
    if (t < PIX) e = __expf(myatt - mx);
    red[t] = e;
    __syncthreads();
    for (int o = 128; o > 0; o >>= 1) {
        if (t < o) red[t] += red[t + o];
        __syncthreads();
    }
    const float inv = 1.f / red[0];
    if (t < PIX) {
        float al = e * inv;
        alpha_s[t] = al;
        if (ec == 0) out[(size_t)BATCH * ENC_DIM + b * PIX + t] = al;   // alpha output
    }
    __syncthreads();

    float4 acc = {0.f, 0.f, 0.f, 0.f};
    const float* ebase = enc + (size_t)b * PIX * ENC_DIM + ec * 1024 + t * 4;
    #pragma unroll 4
    for (int p = 0; p < PIX; ++p) {
        float4 x = *(const float4*)(ebase + (size_t)p * ENC_DIM);
        float a = alpha_s[p];
        acc.x += a * x.x; acc.y += a * x.y; acc.z += a * x.z; acc.w += a * x.w;
    }
    *(float4*)(out + (size_t)b * ENC_DIM + ec * 1024 + t * 4) = acc;
}

extern "C" void kernel_launch(void* const* d_in, const int* in_sizes, int n_in,
                              void* d_out, int out_size, void* d_ws, size_t ws_size,
                              hipStream_t stream) {
    const float* enc    = (const float*)d_in[0];
    const float* dec    = (const float*)d_in[1];
    const float* W_enc  = (const float*)d_in[2];
    const float* b_enc  = (const float*)d_in[3];
    const float* W_dec  = (const float*)d_in[4];
    const float* b_dec  = (const float*)d_in[5];
    const float* W_full = (const float*)d_in[6];
    // d_in[7] (b_full) unused: softmax is shift-invariant, att is not an output.

    char* ws = (char*)d_ws;
    u16*   Wb    = (u16*)ws;                                    // 2 MB bf16 W_enc
    float* att2f = (float*)(ws + 2 * 1024 * 1024);              // 512 KB
    float* att_p = (float*)(ws + 2 * 1024 * 1024 + 512 * 1024); // 4 * 50176 * 4 B

    hipLaunchKernelGGL(k_convert, dim3(512), dim3(256), 0, stream, W_enc, Wb);
    hipLaunchKernelGGL(k_att2,    dim3(256), dim3(256), 0, stream, dec, W_dec, b_enc, b_dec, att2f);
    hipLaunchKernelGGL(k_gemm,    dim3(784), dim3(512), 0, stream, enc, Wb, att2f, W_full, att_p);
    hipLaunchKernelGGL(k_soft,    dim3(512), dim3(256), 0, stream, att_p, enc, (float*)d_out);
}

// Round 9
// 259.937 us; speedup vs baseline: 1.4284x; 1.4284x over previous
//
#include <hip/hip_runtime.h>
#include <hip/hip_bf16.h>
#include <stdint.h>

#define ENC_DIM 2048
#define DEC_DIM 512
#define ATT_DIM 512
#define BATCH   256
#define PIX     196
#define M_TOTAL (BATCH*PIX)   // 50176
#define NT      (ENC_DIM/64)  // 32 K-tiles

typedef unsigned short u16;
typedef __attribute__((ext_vector_type(8))) short  bf16x8;
typedef __attribute__((ext_vector_type(4))) float  f32x4;

// ---------- helpers ----------
__device__ __forceinline__ void gll16(const void* g, void* l) {
    __builtin_amdgcn_global_load_lds(
        (const __attribute__((address_space(1))) unsigned int*)g,
        (__attribute__((address_space(3))) unsigned int*)l,
        16, 0, 0);
}

union Pack8 {
    uint4 u;
    __hip_bfloat16 h[8];
};

__device__ __forceinline__ uint4 cvt8(float4 a, float4 b) {
    Pack8 p;
    p.h[0] = __float2bfloat16(a.x); p.h[1] = __float2bfloat16(a.y);
    p.h[2] = __float2bfloat16(a.z); p.h[3] = __float2bfloat16(a.w);
    p.h[4] = __float2bfloat16(b.x); p.h[5] = __float2bfloat16(b.y);
    p.h[6] = __float2bfloat16(b.z); p.h[7] = __float2bfloat16(b.w);
    return p.u;
}

// ---------- kernel 1: W_enc fp32 -> bf16 ----------
__global__ void k_convert(const float* __restrict__ W, u16* __restrict__ Wb) {
    int idx = blockIdx.x * 256 + threadIdx.x;
    const float4* s = (const float4*)W + (size_t)idx * 2;
    ((uint4*)Wb)[idx] = cvt8(s[0], s[1]);
}

// ---------- kernel 2: att2[b,a] = dec[b,:].W_dec[a,:] + b_enc[a] + b_dec[a] ----------
__global__ void k_att2(const float* __restrict__ dec, const float* __restrict__ Wd,
                       const float* __restrict__ b_enc, const float* __restrict__ b_dec,
                       float* __restrict__ att2f) {
    int b = blockIdx.x;
    int t = threadIdx.x;
    __shared__ float dec_s[DEC_DIM];
    ((float2*)dec_s)[t] = ((const float2*)(dec + (size_t)b * DEC_DIM))[t];
    __syncthreads();
    #pragma unroll
    for (int rep = 0; rep < 2; ++rep) {
        int a = t + rep * 256;
        const float4* w = (const float4*)(Wd + (size_t)a * DEC_DIM);
        float acc = 0.f;
        #pragma unroll 4
        for (int e = 0; e < DEC_DIM / 4; ++e) {
            float4 wv = w[e];
            float4 dv = ((const float4*)dec_s)[e];
            acc += wv.x * dv.x + wv.y * dv.y + wv.z * dv.z + wv.w * dv.w;
        }
        att2f[(size_t)b * ATT_DIM + a] = acc + b_enc[a] + b_dec[a];
    }
}

// ---------- kernel 3: fused GEMM, BN=512, BM=128, FULL double-buffer ----------
// 512 threads = 8 waves (2M x 4N), per-wave 64x128. LDS 160KB exact:
//   A dbuf 2x16KB (reg-staged fp32->bf16, swizzled write),
//   B dbuf 2x64KB (gll16, pre-swizzled source; Wb is L2-resident).
// ONE barrier per K-tile: staging for kt+1 is issued BEFORE COMPUTE(kt), so
// the gll16 L2 round-trip lands under the MFMA phase; VMC(4) drains the 8
// gll16 (oldest in FIFO) and keeps the 4 A-prefetch loads (newest) in flight.

#define FENCE  asm volatile("" ::: "memory")
#define LGKM0  asm volatile("s_waitcnt lgkmcnt(0)" ::: "memory")
#define VMC(N) asm volatile("s_waitcnt vmcnt(" #N ")" ::: "memory")
#define SBARF  do { FENCE; __builtin_amdgcn_s_barrier(); FENCE; } while (0)

// 4 fp32x4 loads for A-tile KT: thread t covers rows {0,64}+(t>>3), octet t&7
#define ISSUE_A(KT, F) do { const float* _p = a_src + (size_t)(KT) * 64;               \
    F[0] = *(const float4*)(_p);                                                       \
    F[1] = *(const float4*)(_p + 4);                                                   \
    F[2] = *(const float4*)(_p + (size_t)64 * ENC_DIM);                                \
    F[3] = *(const float4*)(_p + (size_t)64 * ENC_DIM + 4); } while (0)

// cvt + 2 swizzled ds_write_b128 into As[Q] (implicit wait on F's loads here;
// those loads had a full tile in flight -> near-free)
#define WRITE_A(Q, F) do {                                                             \
    *(uint4*)(&As[Q][aw_off])        = cvt8(F[0], F[1]);                               \
    *(uint4*)(&As[Q][aw_off + 4096]) = cvt8(F[2], F[3]); } while (0)

// 8 gll16 staging the 512x64 B-tile KT into Bs[Q]
#define STAGE_B(KT, Q) do { const u16* _b = b_src + (size_t)(KT) * 64;                 \
    _Pragma("unroll") for (int s = 0; s < 8; ++s)                                      \
        gll16(_b + (size_t)s * 64 * ENC_DIM, &Bs[Q][s * 4096 + b_dst]); } while (0)

#define COMPUTE(P) do {                                                                \
    _Pragma("unroll") for (int ks = 0; ks < 2; ++ks) {                                 \
        const int _axo = ks ? axo1 : axo0;                                             \
        bf16x8 af[4], bf[8];                                                           \
        _Pragma("unroll") for (int m = 0; m < 4; ++m)                                  \
            af[m] = *(const bf16x8*)(&As[P][a_row_off + m * 1024 + _axo]);             \
        _Pragma("unroll") for (int n = 0; n < 8; ++n)                                  \
            bf[n] = *(const bf16x8*)(&Bs[P][b_row_off + n * 1024 + _axo]);             \
        __builtin_amdgcn_s_setprio(1);                                                 \
        _Pragma("unroll") for (int m = 0; m < 4; ++m)                                  \
            _Pragma("unroll") for (int n = 0; n < 8; ++n)                              \
                acc[m][n] = __builtin_amdgcn_mfma_f32_16x16x32_bf16(af[m], bf[n], acc[m][n], 0, 0, 0); \
        __builtin_amdgcn_s_setprio(0);                                                 \
    } } while (0)

__global__ void __launch_bounds__(512, 1)
k_gemm(const float* __restrict__ enc, const u16* __restrict__ Wb,
       const float* __restrict__ att2f, const float* __restrict__ Wfull,
       float* __restrict__ att_part) {
    const int mb = blockIdx.x;                 // 392 blocks, BN covers all of N
    const int t  = threadIdx.x;
    const int lane = t & 63, wave = t >> 6;
    const int wm = wave >> 2, wn = wave & 3;   // 2M x 4N wave grid
    const int fr = lane & 15, fq = lane >> 4;

    __shared__ u16 As[2][128 * 64];  // 2 x 16 KB
    __shared__ u16 Bs[2][512 * 64];  // 2 x 64 KB  (total LDS 160 KB exact)

    f32x4 acc[4][8];
    #pragma unroll
    for (int m = 0; m < 4; ++m)
        #pragma unroll
        for (int n = 0; n < 8; ++n)
            acc[m][n] = (f32x4){0.f, 0.f, 0.f, 0.f};

    // A staging: thread t covers rows {0,64} + (t>>3), k-octet t&7
    const int arow  = t >> 3;        // 0..63
    const int aslot = t & 7;
    const float* a_src = enc + (size_t)(mb * 128 + arow) * ENC_DIM + aslot * 8;
    const int aw_off = arow * 64 + ((aslot ^ (arow & 7))) * 8;   // +4096 for row+64

    // B staging via gll16: lane covers row s*64 + wave*8 + (l>>3), slot l&7;
    // source octet pre-swizzled (rule #21), dest linear (HW adds lane*16B)
    const int brl = lane >> 3, bslot = lane & 7;
    const u16* b_src = Wb + (size_t)(wave * 8 + brl) * ENC_DIM + ((bslot ^ brl)) * 8;
    const int b_dst = (wave * 8) * 64;

    // fragment reads: A row = wm*64 + m*16 + fr; B row = wn*128 + n*16 + fr;
    // slot = ((ks<<2)|fq) ^ (fr&7)
    const int r7 = fr & 7;
    const int axo0 = ((fq    ) ^ r7) * 8;
    const int axo1 = ((fq | 4) ^ r7) * 8;
    const int a_row_off = (wm * 64 + fr) * 64;
    const int b_row_off = (wn * 128 + fr) * 64;

    float4 eE[4], eO[4];   // 2-deep A-reg pipeline, parity-named (rule #20)

    // ---- prologue (gll16 before next A-issue: FIFO order) ----
    ISSUE_A(0, eE); FENCE;
    STAGE_B(0, 0);
    WRITE_A(0, eE);        // implicit wait on A(0) regs (gll16 newer, stay)
    FENCE; ISSUE_A(1, eO);
    VMC(4);                // completes 8 gll16(0); keeps A(1) x4 in flight
    LGKM0;
    SBARF;                 // Bs[0]=B(0), As[0]=A(0) visible

    // ---- main loop: tiles 0..29, one barrier per tile ----
    for (int kt = 0; kt < NT - 2; kt += 2) {
        // even tile kt (P=0): stage kt+1 -> buf1 BEFORE compute
        WRITE_A(1, eO);                // A(kt+1) -> As[1] (regs had a full tile)
        STAGE_B(kt + 1, 1); FENCE;     // gll16 first (oldest in FIFO)
        ISSUE_A(kt + 2, eE);           // A prefetch second (newest)
        COMPUTE(0);                    // gll16 flight hides under MFMA
        VMC(4);                        // drains gll16(kt+1); keeps A(kt+2)
        LGKM0;
        SBARF;
        // odd tile kt+1 (P=1): stage kt+2 -> buf0
        WRITE_A(0, eE);
        STAGE_B(kt + 2, 0); FENCE;
        ISSUE_A(kt + 3, eO);
        COMPUTE(1);
        VMC(4);
        LGKM0;
        SBARF;
    }

    // ---- tile 30 (P=0): stage tile 31 -> buf1, no more A issues ----
    {
        WRITE_A(1, eO);                // A(31) -> As[1]
        STAGE_B(31, 1);
        COMPUTE(0);
        VMC(0);                        // full drain
        LGKM0;
        SBARF;
    }
    // ---- tile 31 (P=1): pure compute ----
    COMPUTE(1);

    // ---- epilogue: +att2, relu, dot W_full, 16-lane reduce ----
    // C/D layout: col = lane&15, row = (lane>>4)*4 + reg  [m89/m91]
    const int row_base = mb * 128 + wm * 64 + fq * 4;
    const int col_base = wn * 128 + fr;
    float wf[8];
    #pragma unroll
    for (int n = 0; n < 8; ++n) wf[n] = Wfull[col_base + n * 16];

    #pragma unroll
    for (int m = 0; m < 4; ++m) {
        #pragma unroll
        for (int r = 0; r < 4; ++r) {
            const int grow = row_base + m * 16 + r;
            const int bidx = grow / PIX;
            const float* a2 = att2f + (size_t)bidx * ATT_DIM;
            float ssum = 0.f;
            #pragma unroll
            for (int n = 0; n < 8; ++n) {
                float v = acc[m][n][r] + a2[col_base + n * 16];
                v = fmaxf(v, 0.f);
                ssum += v * wf[n];
            }
            #pragma unroll
            for (int off = 1; off < 16; off <<= 1)
                ssum += __shfl_xor(ssum, off, 64);
            if (fr == 0)
                att_part[(size_t)wn * M_TOTAL + grow] = ssum;
        }
    }
}

// ---------- kernel 4: per-b softmax over 196 + alpha-weighted enc reduction ----------
__global__ void k_soft(const float* __restrict__ att_part, const float* __restrict__ enc,
                       float* __restrict__ out) {
    const int b  = blockIdx.x >> 1;
    const int ec = blockIdx.x & 1;   // e-chunk of 1024
    const int t  = threadIdx.x;
    __shared__ float red[256];
    __shared__ float alpha_s[PIX];

    float myatt = -1e30f;
    if (t < PIX) {
        float s = 0.f;
        #pragma unroll
        for (int j = 0; j < 4; ++j) s += att_part[(size_t)j * M_TOTAL + b * PIX + t];
        myatt = s;
    }
    red[t] = myatt;
    __syncthreads();
    for (int o = 128; o > 0; o >>= 1) {
        if (t < o) red[t] = fmaxf(red[t], red[t + o]);
        __syncthreads();
    }
    const float mx = red[0];
    __syncthreads();
    float e = 0.f;
    if (t < PIX) e = __expf(myatt - mx);
    red[t] = e;
    __syncthreads();
    for (int o = 128; o > 0; o >>= 1) {
        if (t < o) red[t] += red[t + o];
        __syncthreads();
    }
    const float inv = 1.f / red[0];
    if (t < PIX) {
        float al = e * inv;
        alpha_s[t] = al;
        if (ec == 0) out[(size_t)BATCH * ENC_DIM + b * PIX + t] = al;   // alpha output
    }
    __syncthreads();

    float4 acc = {0.f, 0.f, 0.f, 0.f};
    const float* ebase = enc + (size_t)b * PIX * ENC_DIM + ec * 1024 + t * 4;
    #pragma unroll 4
    for (int p = 0; p < PIX; ++p) {
        float4 x = *(const float4*)(ebase + (size_t)p * ENC_DIM);
        float a = alpha_s[p];
        acc.x += a * x.x; acc.y += a * x.y; acc.z += a * x.z; acc.w += a * x.w;
    }
    *(float4*)(out + (size_t)b * ENC_DIM + ec * 1024 + t * 4) = acc;
}

extern "C" void kernel_launch(void* const* d_in, const int* in_sizes, int n_in,
                              void* d_out, int out_size, void* d_ws, size_t ws_size,
                              hipStream_t stream) {
    const float* enc    = (const float*)d_in[0];
    const float* dec    = (const float*)d_in[1];
    const float* W_enc  = (const float*)d_in[2];
    const float* b_enc  = (const float*)d_in[3];
    const float* W_dec  = (const float*)d_in[4];
    const float* b_dec  = (const float*)d_in[5];
    const float* W_full = (const float*)d_in[6];
    // d_in[7] (b_full) unused: softmax is shift-invariant, att is not an output.

    char* ws = (char*)d_ws;
    u16*   Wb    = (u16*)ws;                                    // 2 MB bf16 W_enc
    float* att2f = (float*)(ws + 2 * 1024 * 1024);              // 512 KB
    float* att_p = (float*)(ws + 2 * 1024 * 1024 + 512 * 1024); // 4 * 50176 * 4 B

    hipLaunchKernelGGL(k_convert, dim3(512), dim3(256), 0, stream, W_enc, Wb);
    hipLaunchKernelGGL(k_att2,    dim3(256), dim3(256), 0, stream, dec, W_dec, b_enc, b_dec, att2f);
    hipLaunchKernelGGL(k_gemm,    dim3(392), dim3(512), 0, stream, enc, Wb, att2f, W_full, att_p);
    hipLaunchKernelGGL(k_soft,    dim3(512), dim3(256), 0, stream, att_p, enc, (float*)d_out);
}